// Round 6
// baseline (111.877 us; speedup 1.0000x reference)
//
#include <hip/hip_runtime.h>

// DynamicWeights, 3 kernels: weight-transpose prep + conv/softmax + combine.
// K0: w2[c][k*9+p] = cw[k][c][p]  (c-major contiguous weight stream for s_loads)
// K1: conv3x3 (64ch -> 9 logits), 2 vertical px/thread, softmax,
//     fold gamma/sum -> fs[9] planes in d_ws.
// K2: out[c] = sum_p fs_p * x[c,tap_p] + x[c,center]  (streaming, near HBM floor)
// x: (8,64,192,192) f32, conv_w: (9,64,3,3) f32, gamma: (1,) f32

constexpr int Nn = 8, Cc = 64, Hh = 192, Ww = 192;
constexpr int HW  = Hh * Ww;
constexpr int NPX = Nn * HW;           // 294912
constexpr int W2N = Cc * 81;           // 5184 floats
constexpr int FS_OFF = 8192;           // fs starts 32 KB into d_ws (aligned)

// ---- K0: weight transpose ----
__global__ __launch_bounds__(256)
void k_wtrans(const float* __restrict__ cw, float* __restrict__ w2) {
    int i = blockIdx.x * 256 + threadIdx.x;
    if (i < W2N) {
        int c = i / 81, r = i - c * 81;
        int k = r / 9,  p = r - k * 9;
        w2[i] = cw[(k * Cc + c) * 9 + p];
    }
}

// ---- K1: conv + softmax, 2 vertical pixels per thread ----
__global__ __launch_bounds__(256)
void k_conv(const float* __restrict__ x, const float* __restrict__ w2,
            const float* __restrict__ gamma, float* __restrict__ fs)
{
    const int tx = threadIdx.x & 63, tq = threadIdx.x >> 6;
    const int w = blockIdx.x * 64 + tx;
    const int h = blockIdx.y * 8 + tq * 2;      // this thread: rows h, h+1
    const int n = blockIdx.z;

    // 12 taps: rows h-1..h+2, cols w-1..w+1 (clamped offsets + masks, branch-free)
    int boff[4][3]; float msk[4][3];
#pragma unroll
    for (int r = 0; r < 4; ++r) {
        int hh = h + r - 1;
        bool vr = (unsigned)hh < (unsigned)Hh;
        int hc = min(max(hh, 0), Hh - 1);
#pragma unroll
        for (int j = 0; j < 3; ++j) {
            int ww = w + j - 1;
            bool v = vr && ((unsigned)ww < (unsigned)Ww);
            int wcl = min(max(ww, 0), Ww - 1);
            boff[r][j] = (hc * Ww + wcl) * 4;
            msk[r][j]  = v ? 1.f : 0.f;
        }
    }

    const char* xn = (const char*)(x + (size_t)n * Cc * HW);

    float d0[9], d1[9];
#pragma unroll
    for (int k = 0; k < 9; ++k) { d0[k] = 0.f; d1[k] = 0.f; }

#pragma unroll 2
    for (int c = 0; c < Cc; ++c) {
        const char* xc = xn + (size_t)c * HW * 4;   // wave-uniform base
        float xv[4][3];
#pragma unroll
        for (int r = 0; r < 4; ++r)
#pragma unroll
            for (int j = 0; j < 3; ++j)
                xv[r][j] = *(const float*)(xc + boff[r][j]) * msk[r][j];
        const float* wc = w2 + c * 81;              // sequential scalar stream
#pragma unroll
        for (int k = 0; k < 9; ++k) {
#pragma unroll
            for (int p = 0; p < 9; ++p) {
                const float wv = wc[k * 9 + p];
                const int di = p / 3, dj = p - di * 3;
                d0[k] = fmaf(xv[di][dj],     wv, d0[k]);
                d1[k] = fmaf(xv[di + 1][dj], wv, d1[k]);
            }
        }
    }

    const float g = gamma[0];
    const int pxflat = n * HW + h * Ww + w;

    // softmax px0 (fold gamma/sum)
    {
        float m = d0[0];
#pragma unroll
        for (int k = 1; k < 9; ++k) m = fmaxf(m, d0[k]);
        float e[9], s = 0.f;
#pragma unroll
        for (int k = 0; k < 9; ++k) { e[k] = __expf(d0[k] - m); s += e[k]; }
        const float gs = g / s;
#pragma unroll
        for (int k = 0; k < 9; ++k)
            fs[(size_t)k * NPX + pxflat] = e[k] * gs;
    }
    // softmax px1 (row h+1, always in-image)
    {
        float m = d1[0];
#pragma unroll
        for (int k = 1; k < 9; ++k) m = fmaxf(m, d1[k]);
        float e[9], s = 0.f;
#pragma unroll
        for (int k = 0; k < 9; ++k) { e[k] = __expf(d1[k] - m); s += e[k]; }
        const float gs = g / s;
#pragma unroll
        for (int k = 0; k < 9; ++k)
            fs[(size_t)k * NPX + pxflat + Ww] = e[k] * gs;
    }
}

// ---- K2: weighted combine + residual (unchanged from R4) ----
__global__ __launch_bounds__(256)
void k_comb(const float* __restrict__ x, const float* __restrict__ fs,
            float* __restrict__ out)
{
    const int tx = threadIdx.x & 63, ty = threadIdx.x >> 6;
    const int w = blockIdx.x * 64 + tx;
    const int h = blockIdx.y * 4 + ty;
    const int n = blockIdx.z;

    int boff[9]; float msk[9];
#pragma unroll
    for (int di = 0; di < 3; ++di)
#pragma unroll
        for (int dj = 0; dj < 3; ++dj) {
            int hh = h + di - 1, ww = w + dj - 1;
            bool v = ((unsigned)hh < (unsigned)Hh) && ((unsigned)ww < (unsigned)Ww);
            int hc = min(max(hh, 0), Hh - 1);
            int wcl = min(max(ww, 0), Ww - 1);
            boff[di * 3 + dj] = (hc * Ww + wcl) * 4;
            msk[di * 3 + dj] = v ? 1.f : 0.f;
        }

    const int pxflat = n * HW + h * Ww + w;
    float f[9];
#pragma unroll
    for (int p = 0; p < 9; ++p)
        f[p] = fs[(size_t)p * NPX + pxflat] * msk[p];

    const char* xn = (const char*)(x + (size_t)n * Cc * HW);
    float* outp = out + (size_t)n * Cc * HW + h * Ww + w;

#pragma unroll 2
    for (int c = 0; c < Cc; ++c) {
        const char* xc = xn + (size_t)c * HW * 4;
        float acc = 0.f;
#pragma unroll
        for (int p = 0; p < 9; ++p)
            acc = fmaf(*(const float*)(xc + boff[p]), f[p], acc);
        const float xcen = *(const float*)(xc + boff[4]);
        outp[(size_t)c * HW] = acc + xcen;
    }
}

extern "C" void kernel_launch(void* const* d_in, const int* in_sizes, int n_in,
                              void* d_out, int out_size, void* d_ws, size_t ws_size,
                              hipStream_t stream) {
    const float* x  = (const float*)d_in[0];
    const float* cw = (const float*)d_in[1];
    const float* gm = (const float*)d_in[2];
    float* out = (float*)d_out;
    float* w2  = (float*)d_ws;                 // 5184 floats
    float* fs  = (float*)d_ws + FS_OFF;        // 9 * 294912 floats = 10.6 MB

    dim3 block(256);
    k_wtrans<<<dim3((W2N + 255) / 256), block, 0, stream>>>(cw, w2);
    k_conv <<<dim3(3, 24, 8), block, 0, stream>>>(x, w2, gm, fs);
    k_comb <<<dim3(3, 48, 8), block, 0, stream>>>(x, fs, out);
}

// Round 7
// 87.938 us; speedup vs baseline: 1.2722x; 1.2722x over previous
//
#include <hip/hip_runtime.h>

// DynamicWeights, 3 kernels:
//  K0 wprep: weights -> MFMA A-fragment blob (bf16), rows 9..15 zeroed.
//  K1 k_conv: implicit-GEMM conv via mfma_f32_16x16x32_bf16:
//     D[16 logits][16 px] = W[16x576] * patches[576 x 16px], K = tap(9) x ch(64).
//     LDS: x-tile transposed [row][col][ch] bf16, XOR-swizzled. Softmax via
//     shfl_xor(16/32), gamma/sum folded -> fs[9] planes (f32) in d_ws.
//  K2 k_comb: out[c] = sum_p fs_p * x[c,tap_p] + x[c,center]  (f32 streaming).
// x: (8,64,192,192) f32, conv_w: (9,64,3,3) f32, gamma: (1,) f32

constexpr int Nn = 8, Cc = 64, Hh = 192, Ww = 192;
constexpr int HW  = Hh * Ww;
constexpr int NPX = Nn * HW;            // 294912
constexpr int NKB = 18;                 // K-blocks: 576/32
constexpr int BLOB_N = NKB * 64 * 8;    // 9216 bf16
constexpr int FS_OFF = 8192;            // fs at float offset 8192 (32 KB) in d_ws

typedef short  bf16x8 __attribute__((ext_vector_type(8)));
typedef float  f32x4  __attribute__((ext_vector_type(4)));

__device__ __forceinline__ unsigned short f2b(float f) {
    union { float f; unsigned u; } v; v.f = f;
    return (unsigned short)((v.u + 0x7FFF + ((v.u >> 16) & 1)) >> 16);
}

// ---- K0: weight blob in A-fragment layout ----
// blob[kb*512 + lane*8 + j] = (m<9) ? w[m][c][p] : 0,
//   m = lane&15, k = kb*32 + (lane>>4)*8 + j, p = k>>6, c = k&63.
__global__ __launch_bounds__(256)
void k_wprep(const float* __restrict__ cw, unsigned short* __restrict__ blob) {
    int idx = blockIdx.x * 256 + threadIdx.x;
    if (idx < BLOB_N) {
        int j  = idx & 7;
        int l  = (idx >> 3) & 63;
        int kb = idx >> 9;
        int k  = kb * 32 + ((l >> 4) << 3) + j;
        int m  = l & 15;
        int p  = k >> 6, c = k & 63;
        float v = (m < 9) ? cw[(m * Cc + c) * 9 + p] : 0.f;
        blob[idx] = f2b(v);
    }
}

// ---- K1: MFMA conv + softmax ----
__global__ __launch_bounds__(256, 3)
void k_conv(const float* __restrict__ x, const unsigned short* __restrict__ blob,
            const float* __restrict__ gamma, float* __restrict__ fs)
{
    __shared__ short xs[6 * 66 * 64];   // 50688 B, swizzled [row][col][ch]

    const int tid  = threadIdx.x;
    const int lane = tid & 63, q = tid >> 6;      // wave q owns pixel row h0+q
    const int w0 = blockIdx.x * 64, h0 = blockIdx.y * 4, n = blockIdx.z;
    const float* __restrict__ xn = x + (size_t)n * Cc * HW;

    // A-frags: 18 x dwordx4, coalesced, L2-hot after first blocks
    bf16x8 af[NKB];
#pragma unroll
    for (int kb = 0; kb < NKB; ++kb)
        af[kb] = *(const bf16x8*)(blob + (kb * 64 + lane) * 8);

    // stage tile: (row 0..5, col 0..65, cgrp 0..7) -> 8 ch per b128 write
#pragma unroll 4
    for (int i = 0; i < 13; ++i) {
        int idx = tid + i * 256;
        if (idx < 3168) {
            int col  = idx % 66;
            int rest = idx / 66;
            int row  = rest % 6, cg = rest / 6;
            int gh = h0 + row - 1, gw = w0 + col - 1;
            bool ok = ((unsigned)gh < (unsigned)Hh) && ((unsigned)gw < (unsigned)Ww);
            const float* src = xn + (size_t)(cg * 8) * HW + gh * Ww + gw;
            float v[8];
#pragma unroll
            for (int j = 0; j < 8; ++j)
                v[j] = ok ? src[(size_t)j * HW] : 0.f;
            unsigned u0 = (unsigned)f2b(v[0]) | ((unsigned)f2b(v[1]) << 16);
            unsigned u1 = (unsigned)f2b(v[2]) | ((unsigned)f2b(v[3]) << 16);
            unsigned u2 = (unsigned)f2b(v[4]) | ((unsigned)f2b(v[5]) << 16);
            unsigned u3 = (unsigned)f2b(v[6]) | ((unsigned)f2b(v[7]) << 16);
            int widx = (row * 66 + col) * 64 + ((cg ^ (col & 7)) << 3);
            *(int4*)&xs[widx] = make_int4(u0, u1, u2, u3);
        }
    }
    __syncthreads();

    // per-lane swizzled base for (dj, chunk): col = (lane&15)+mt*16+dj
    const int g8 = ((lane >> 4) << 3);
    int B[3][2];
#pragma unroll
    for (int dj = 0; dj < 3; ++dj) {
        int colp = (lane & 15) + dj;
        int swz  = (colp & 7) << 3;
        int rc   = (q * 66 + colp) * 64;
#pragma unroll
        for (int ch = 0; ch < 2; ++ch)
            B[dj][ch] = rc + (((ch << 5) | g8) ^ swz);
    }

    f32x4 z = {0.f, 0.f, 0.f, 0.f};
    f32x4 acc0 = z, acc1 = z, acc2 = z, acc3 = z;

#pragma unroll
    for (int kb = 0; kb < NKB; ++kb) {
        const int p = kb >> 1, di = p / 3, dj = p % 3, ch = kb & 1;
        const int ofs = B[dj][ch] + di * (66 * 64);
        bf16x8 b0 = *(const bf16x8*)&xs[ofs + 0 * 1024];
        bf16x8 b1 = *(const bf16x8*)&xs[ofs + 1 * 1024];
        bf16x8 b2 = *(const bf16x8*)&xs[ofs + 2 * 1024];
        bf16x8 b3 = *(const bf16x8*)&xs[ofs + 3 * 1024];
        acc0 = __builtin_amdgcn_mfma_f32_16x16x32_bf16(af[kb], b0, acc0, 0, 0, 0);
        acc1 = __builtin_amdgcn_mfma_f32_16x16x32_bf16(af[kb], b1, acc1, 0, 0, 0);
        acc2 = __builtin_amdgcn_mfma_f32_16x16x32_bf16(af[kb], b2, acc2, 0, 0, 0);
        acc3 = __builtin_amdgcn_mfma_f32_16x16x32_bf16(af[kb], b3, acc3, 0, 0, 0);
    }

    // softmax over 9 logits per pixel; lane holds logits gidx*4..+3 of pixel lane&15
    const float g0 = gamma[0];
    const int gidx = lane >> 4;
    const size_t pxbase = (size_t)n * HW + (size_t)(h0 + q) * Ww + w0 + (lane & 15);
    const int k0 = gidx * 4;
    const float NEG = -3.0e38f;

    f32x4 accs[4] = {acc0, acc1, acc2, acc3};
#pragma unroll
    for (int mt = 0; mt < 4; ++mt) {
        float a0 = accs[mt][0], a1 = accs[mt][1], a2 = accs[mt][2], a3 = accs[mt][3];
        float m0 = (gidx < 3) ? a0 : NEG;
        float m1 = (gidx < 2) ? a1 : NEG;
        float m2 = (gidx < 2) ? a2 : NEG;
        float m3 = (gidx < 2) ? a3 : NEG;
        float m = fmaxf(fmaxf(m0, m1), fmaxf(m2, m3));
        m = fmaxf(m, __shfl_xor(m, 16));
        m = fmaxf(m, __shfl_xor(m, 32));
        float e0 = (gidx < 3) ? __expf(a0 - m) : 0.f;
        float e1 = (gidx < 2) ? __expf(a1 - m) : 0.f;
        float e2 = (gidx < 2) ? __expf(a2 - m) : 0.f;
        float e3 = (gidx < 2) ? __expf(a3 - m) : 0.f;
        float s = (e0 + e1) + (e2 + e3);
        s += __shfl_xor(s, 16);
        s += __shfl_xor(s, 32);
        const float gs = g0 / s;
        const size_t px = pxbase + mt * 16;
        if (gidx < 3) fs[(size_t)k0 * NPX + px] = e0 * gs;
        if (gidx < 2) {
            fs[(size_t)(k0 + 1) * NPX + px] = e1 * gs;
            fs[(size_t)(k0 + 2) * NPX + px] = e2 * gs;
            fs[(size_t)(k0 + 3) * NPX + px] = e3 * gs;
        }
    }
}

// ---- K2: weighted combine + residual (R4/R6-validated) ----
__global__ __launch_bounds__(256)
void k_comb(const float* __restrict__ x, const float* __restrict__ fs,
            float* __restrict__ out)
{
    const int tx = threadIdx.x & 63, ty = threadIdx.x >> 6;
    const int w = blockIdx.x * 64 + tx;
    const int h = blockIdx.y * 4 + ty;
    const int n = blockIdx.z;

    int boff[9]; float msk[9];
#pragma unroll
    for (int di = 0; di < 3; ++di)
#pragma unroll
        for (int dj = 0; dj < 3; ++dj) {
            int hh = h + di - 1, ww = w + dj - 1;
            bool v = ((unsigned)hh < (unsigned)Hh) && ((unsigned)ww < (unsigned)Ww);
            int hc  = min(max(hh, 0), Hh - 1);
            int wcl = min(max(ww, 0), Ww - 1);
            boff[di * 3 + dj] = (hc * Ww + wcl) * 4;
            msk[di * 3 + dj] = v ? 1.f : 0.f;
        }

    const int pxflat = n * HW + h * Ww + w;
    float f[9];
#pragma unroll
    for (int p = 0; p < 9; ++p)
        f[p] = fs[(size_t)p * NPX + pxflat] * msk[p];

    const char* xn = (const char*)(x + (size_t)n * Cc * HW);
    float* outp = out + (size_t)n * Cc * HW + h * Ww + w;

#pragma unroll 2
    for (int c = 0; c < Cc; ++c) {
        const char* xc = xn + (size_t)c * HW * 4;
        float acc = 0.f;
#pragma unroll
        for (int p = 0; p < 9; ++p)
            acc = fmaf(*(const float*)(xc + boff[p]), f[p], acc);
        const float xcen = *(const float*)(xc + boff[4]);
        outp[(size_t)c * HW] = acc + xcen;
    }
}

extern "C" void kernel_launch(void* const* d_in, const int* in_sizes, int n_in,
                              void* d_out, int out_size, void* d_ws, size_t ws_size,
                              hipStream_t stream) {
    const float* x  = (const float*)d_in[0];
    const float* cw = (const float*)d_in[1];
    const float* gm = (const float*)d_in[2];
    float* out = (float*)d_out;
    unsigned short* blob = (unsigned short*)d_ws;      // 9216 bf16 = 18 KB
    float* fs = (float*)d_ws + FS_OFF;                 // 9 * 294912 f32 = 10.6 MB

    dim3 block(256);
    k_wprep<<<dim3((BLOB_N + 255) / 256), block, 0, stream>>>(cw, blob);
    k_conv <<<dim3(3, 48, 8), block, 0, stream>>>(x, blob, gm, fs);
    k_comb <<<dim3(3, 48, 8), block, 0, stream>>>(x, fs, out);
}

// Round 8
// 69.188 us; speedup vs baseline: 1.6170x; 1.2710x over previous
//
#include <hip/hip_runtime.h>

// DynamicWeights, fully fused MFMA kernel + weight-prep.
//  K0 k_wprep: weights -> MFMA A-fragment blob (bf16), rows 9..15 zeroed.
//  K1 k_main: stage x-tile (32x8 px + halo, 64ch, bf16, XOR-swizzled) in LDS once;
//     conv via mfma_f32_16x16x32_bf16; softmax via shfl; redistribute filter
//     (bf16) wave->pixel through LDS; combine + residual straight from the
//     SAME LDS tile; write out. x staged once, no fs round-trip.
// x: (8,64,192,192) f32, conv_w: (9,64,3,3) f32, gamma: (1,) f32

constexpr int Nn = 8, Cc = 64, Hh = 192, Ww = 192;
constexpr int HW  = Hh * Ww;
constexpr int NKB = 18;                 // K-blocks: 576/32
constexpr int BLOB_N = NKB * 64 * 8;    // 9216 bf16
constexpr int TX = 32, TY = 8;          // pixel tile (256 threads, 1 px/thread)
constexpr int SR = TY + 2, SC = TX + 2; // staged rows/cols: 10 x 34
constexpr int NSTG = SR * SC * 8;       // 2720 b128 stores (8ch each)
constexpr int FBS = 16;                 // fbuf stride (shorts) per pixel

typedef short  bf16x8 __attribute__((ext_vector_type(8)));
typedef float  f32x4  __attribute__((ext_vector_type(4)));

__device__ __forceinline__ unsigned short f2b(float f) {
    union { float f; unsigned u; } v; v.f = f;
    return (unsigned short)((v.u + 0x7FFF + ((v.u >> 16) & 1)) >> 16);
}
__device__ __forceinline__ float b2f(unsigned short s) {
    union { unsigned u; float f; } v; v.u = ((unsigned)s) << 16;
    return v.f;
}

// ---- K0: weight blob in A-fragment layout (validated R7) ----
// blob[kb*512 + lane*8 + j] = (m<9) ? w[m][c][p] : 0,
//   m = lane&15, k = kb*32 + (lane>>4)*8 + j, p = k>>6, c = k&63.
__global__ __launch_bounds__(256)
void k_wprep(const float* __restrict__ cw, unsigned short* __restrict__ blob) {
    int idx = blockIdx.x * 256 + threadIdx.x;
    if (idx < BLOB_N) {
        int j  = idx & 7;
        int l  = (idx >> 3) & 63;
        int kb = idx >> 9;
        int k  = kb * 32 + ((l >> 4) << 3) + j;
        int m  = l & 15;
        int p  = k >> 6, c = k & 63;
        float v = (m < 9) ? cw[(m * Cc + c) * 9 + p] : 0.f;
        blob[idx] = f2b(v);
    }
}

// ---- K1: fused conv + softmax + combine ----
__global__ __launch_bounds__(256, 3)
void k_main(const float* __restrict__ x, const unsigned short* __restrict__ blob,
            const float* __restrict__ gamma, float* __restrict__ out)
{
    __shared__ short xs[SR * SC * 64];   // 43520 B, swizzled [row][col][ch]
    __shared__ short fb[256 * FBS];      // 8192 B: per-pixel 9 filter taps (bf16)

    const int tid  = threadIdx.x;
    const int lane = tid & 63, q = tid >> 6;
    const int w0 = blockIdx.x * TX, h0 = blockIdx.y * TY, n = blockIdx.z;
    const float* __restrict__ xn = x + (size_t)n * Cc * HW;

    // A-frags (18 x dwordx4, L2-hot)
    bf16x8 af[NKB];
#pragma unroll
    for (int kb = 0; kb < NKB; ++kb)
        af[kb] = *(const bf16x8*)(blob + (kb * 64 + lane) * 8);

    // ---- stage tile: (col, row, cgrp) -> 8 ch per b128 write, XOR-swizzled ----
#pragma unroll 4
    for (int i = 0; i < 11; ++i) {
        int idx = tid + i * 256;
        if (idx < NSTG) {
            int col  = idx % SC;
            int rest = idx / SC;
            int row  = rest % SR, cg = rest / SR;
            int gh = h0 + row - 1, gw = w0 + col - 1;
            bool ok = ((unsigned)gh < (unsigned)Hh) && ((unsigned)gw < (unsigned)Ww);
            const float* src = xn + (size_t)(cg * 8) * HW + gh * Ww + gw;
            float v[8];
#pragma unroll
            for (int j = 0; j < 8; ++j)
                v[j] = ok ? src[(size_t)j * HW] : 0.f;
            unsigned u0 = (unsigned)f2b(v[0]) | ((unsigned)f2b(v[1]) << 16);
            unsigned u1 = (unsigned)f2b(v[2]) | ((unsigned)f2b(v[3]) << 16);
            unsigned u2 = (unsigned)f2b(v[4]) | ((unsigned)f2b(v[5]) << 16);
            unsigned u3 = (unsigned)f2b(v[6]) | ((unsigned)f2b(v[7]) << 16);
            int widx = (row * SC + col) * 64 + ((cg ^ (col & 7)) << 3);
            *(int4*)&xs[widx] = make_int4(u0, u1, u2, u3);
        }
    }
    __syncthreads();

    // ---- MFMA: wave q owns pixel rows 2q,2q+1; px = (lane&15) + 16*mt ----
    const int g8 = (lane >> 4) << 3;
    int cbase[3], chg[3][2];
#pragma unroll
    for (int dj = 0; dj < 3; ++dj) {
        int swz = (((lane & 15) + dj) & 7) << 3;
        chg[dj][0] = g8 ^ swz;
        chg[dj][1] = (32 | g8) ^ swz;
        cbase[dj]  = ((2 * q) * SC + (lane & 15) + dj) * 64;
    }

    f32x4 z = {0.f, 0.f, 0.f, 0.f};
    f32x4 acc0 = z, acc1 = z, acc2 = z, acc3 = z;

#pragma unroll
    for (int kb = 0; kb < NKB; ++kb) {
        const int p = kb >> 1, di = p / 3, dj = p % 3, ch = kb & 1;
        const int a0 = cbase[dj] + di * (SC * 64) + chg[dj][ch];
        bf16x8 b0 = *(const bf16x8*)&xs[a0];                          // mt0
        bf16x8 b1 = *(const bf16x8*)&xs[a0 + 16 * 64];                // mt1: col+16
        bf16x8 b2 = *(const bf16x8*)&xs[a0 + SC * 64];                // mt2: row+1
        bf16x8 b3 = *(const bf16x8*)&xs[a0 + SC * 64 + 16 * 64];      // mt3
        acc0 = __builtin_amdgcn_mfma_f32_16x16x32_bf16(af[kb], b0, acc0, 0, 0, 0);
        acc1 = __builtin_amdgcn_mfma_f32_16x16x32_bf16(af[kb], b1, acc1, 0, 0, 0);
        acc2 = __builtin_amdgcn_mfma_f32_16x16x32_bf16(af[kb], b2, acc2, 0, 0, 0);
        acc3 = __builtin_amdgcn_mfma_f32_16x16x32_bf16(af[kb], b3, acc3, 0, 0, 0);
    }

    // ---- softmax (R7-validated shfl form), filter -> fb[px][k] bf16 ----
    const float g0 = gamma[0];
    const int gidx = lane >> 4;
    const int k0 = gidx * 4;
    const float NEG = -3.0e38f;

    f32x4 accs[4] = {acc0, acc1, acc2, acc3};
#pragma unroll
    for (int mt = 0; mt < 4; ++mt) {
        float a0 = accs[mt][0], a1 = accs[mt][1], a2 = accs[mt][2], a3 = accs[mt][3];
        float m0 = (gidx < 3) ? a0 : NEG;
        float m1 = (gidx < 2) ? a1 : NEG;
        float m2 = (gidx < 2) ? a2 : NEG;
        float m3 = (gidx < 2) ? a3 : NEG;
        float m = fmaxf(fmaxf(m0, m1), fmaxf(m2, m3));
        m = fmaxf(m, __shfl_xor(m, 16));
        m = fmaxf(m, __shfl_xor(m, 32));
        float e0 = (gidx < 3) ? __expf(a0 - m) : 0.f;
        float e1 = (gidx < 2) ? __expf(a1 - m) : 0.f;
        float e2 = (gidx < 2) ? __expf(a2 - m) : 0.f;
        float e3 = (gidx < 2) ? __expf(a3 - m) : 0.f;
        float s = (e0 + e1) + (e2 + e3);
        s += __shfl_xor(s, 16);
        s += __shfl_xor(s, 32);
        const float gs = g0 / s;
        const int px = q * 64 + (lane & 15) + mt * 16;
        if (gidx < 2) {
            unsigned p01 = (unsigned)f2b(e0 * gs) | ((unsigned)f2b(e1 * gs) << 16);
            unsigned p23 = (unsigned)f2b(e2 * gs) | ((unsigned)f2b(e3 * gs) << 16);
            *(unsigned*)&fb[px * FBS + k0]     = p01;
            *(unsigned*)&fb[px * FBS + k0 + 2] = p23;
        } else if (gidx == 2) {
            fb[px * FBS + 8] = f2b(e0 * gs);
        }
    }
    __syncthreads();

    // ---- combine + residual, straight from the staged tile ----
    const int prow = tid >> 5, pcol = tid & 31;   // this thread's pixel
    float f[9];
    {
        int4 u = *(const int4*)&fb[tid * FBS];    // 32-B aligned
        f[0] = b2f((unsigned short)(u.x & 0xffff)); f[1] = b2f((unsigned short)(u.x >> 16));
        f[2] = b2f((unsigned short)(u.y & 0xffff)); f[3] = b2f((unsigned short)(u.y >> 16));
        f[4] = b2f((unsigned short)(u.z & 0xffff)); f[5] = b2f((unsigned short)(u.z >> 16));
        f[6] = b2f((unsigned short)(u.w & 0xffff)); f[7] = b2f((unsigned short)(u.w >> 16));
        f[8] = b2f((unsigned short)fb[tid * FBS + 8]);
    }

    float* outp = out + (size_t)n * Cc * HW + (size_t)(h0 + prow) * Ww + (w0 + pcol);

#pragma unroll 2
    for (int cg = 0; cg < 8; ++cg) {
        float acc[8], cen[8];
#pragma unroll
        for (int j = 0; j < 8; ++j) acc[j] = 0.f;
#pragma unroll
        for (int p = 0; p < 9; ++p) {
            const int di = p / 3, dj = p % 3;
            const int addr = ((prow + di) * SC + pcol + dj) * 64
                           + ((cg ^ ((pcol + dj) & 7)) << 3);
            int4 u = *(const int4*)&xs[addr];
            float v[8];
            v[0] = b2f((unsigned short)(u.x & 0xffff)); v[1] = b2f((unsigned short)(u.x >> 16));
            v[2] = b2f((unsigned short)(u.y & 0xffff)); v[3] = b2f((unsigned short)(u.y >> 16));
            v[4] = b2f((unsigned short)(u.z & 0xffff)); v[5] = b2f((unsigned short)(u.z >> 16));
            v[6] = b2f((unsigned short)(u.w & 0xffff)); v[7] = b2f((unsigned short)(u.w >> 16));
#pragma unroll
            for (int j = 0; j < 8; ++j) {
                if (p == 4) cen[j] = v[j];
                acc[j] = fmaf(f[p], v[j], acc[j]);
            }
        }
#pragma unroll
        for (int j = 0; j < 8; ++j)
            outp[(size_t)(cg * 8 + j) * HW] = acc[j] + cen[j];
    }
}

extern "C" void kernel_launch(void* const* d_in, const int* in_sizes, int n_in,
                              void* d_out, int out_size, void* d_ws, size_t ws_size,
                              hipStream_t stream) {
    const float* x  = (const float*)d_in[0];
    const float* cw = (const float*)d_in[1];
    const float* gm = (const float*)d_in[2];
    float* out = (float*)d_out;
    unsigned short* blob = (unsigned short*)d_ws;   // 9216 bf16 = 18 KB

    dim3 block(256);
    k_wprep<<<dim3((BLOB_N + 255) / 256), block, 0, stream>>>(cw, blob);
    k_main <<<dim3(Ww / TX, Hh / TY, Nn), block, 0, stream>>>(x, blob, gm, out);
}

// Round 9
// 56.571 us; speedup vs baseline: 1.9776x; 1.2230x over previous
//
#include <hip/hip_runtime.h>

// DynamicWeights, fully fused MFMA kernel + weight-prep. R9: 512-thread blocks
// (8 waves) at unchanged 32x8 tile -> 24 waves/CU (2x R8), + XCD-aware block
// swizzle for halo L2 reuse.
//  K0 k_wprep: weights -> MFMA A-fragment blob (bf16), rows 9..15 zeroed.
//  K1 k_main: stage x-tile (32x8 px + halo, 64ch, bf16, XOR-swizzled) in LDS;
//     conv via mfma_f32_16x16x32_bf16 (wave q: pixel row q, 2 m-tiles);
//     softmax via shfl; filter -> fb (bf16); combine + residual from the SAME
//     LDS tile; coalesced dword stores.
// x: (8,64,192,192) f32, conv_w: (9,64,3,3) f32, gamma: (1,) f32

constexpr int Nn = 8, Cc = 64, Hh = 192, Ww = 192;
constexpr int HW  = Hh * Ww;
constexpr int NKB = 18;                 // K-blocks: 576/32
constexpr int BLOB_N = NKB * 64 * 8;    // 9216 bf16
constexpr int TX = 32, TY = 8;          // pixel tile (256 px)
constexpr int SR = TY + 2, SC = TX + 2; // staged rows/cols: 10 x 34
constexpr int NSTG = SR * SC * 8;       // 2720 b128 stores (8ch each)
constexpr int FBS = 16;                 // fbuf stride (shorts) per pixel
constexpr int GX = Ww / TX, GY = Hh / TY;          // 6, 24
constexpr int NWG = GX * GY * Nn;                  // 1152 (% 8 == 0)
constexpr int CPX = NWG / 8;                       // 144 tiles per XCD chunk

typedef short  bf16x8 __attribute__((ext_vector_type(8)));
typedef float  f32x4  __attribute__((ext_vector_type(4)));

__device__ __forceinline__ unsigned short f2b(float f) {
    union { float f; unsigned u; } v; v.f = f;
    return (unsigned short)((v.u + 0x7FFF + ((v.u >> 16) & 1)) >> 16);
}
__device__ __forceinline__ float b2f(unsigned short s) {
    union { unsigned u; float f; } v; v.u = ((unsigned)s) << 16;
    return v.f;
}

// ---- K0: weight blob in A-fragment layout (validated R7/R8) ----
__global__ __launch_bounds__(256)
void k_wprep(const float* __restrict__ cw, unsigned short* __restrict__ blob) {
    int idx = blockIdx.x * 256 + threadIdx.x;
    if (idx < BLOB_N) {
        int j  = idx & 7;
        int l  = (idx >> 3) & 63;
        int kb = idx >> 9;
        int k  = kb * 32 + ((l >> 4) << 3) + j;
        int m  = l & 15;
        int p  = k >> 6, c = k & 63;
        float v = (m < 9) ? cw[(m * Cc + c) * 9 + p] : 0.f;
        blob[idx] = f2b(v);
    }
}

// ---- K1: fused conv + softmax + combine, 8 waves/block ----
__global__ __launch_bounds__(512, 6)   // 6 waves/EU -> 3 blocks/CU (24 waves)
void k_main(const float* __restrict__ x, const unsigned short* __restrict__ blob,
            const float* __restrict__ gamma, float* __restrict__ out)
{
    __shared__ short xs[SR * SC * 64];   // 43520 B, swizzled [row][col][ch]
    __shared__ short fb[256 * FBS];      // 8192 B: per-pixel 9 filter taps (bf16)

    // XCD-aware bijective swizzle (1152 % 8 == 0): XCD k gets 144 contiguous tiles
    const int b  = blockIdx.x;
    const int wt = (b & 7) * CPX + (b >> 3);
    const int bx = wt % GX;
    const int r2 = wt / GX;
    const int by = r2 % GY;
    const int n  = r2 / GY;

    const int tid  = threadIdx.x;
    const int lane = tid & 63, q = tid >> 6;       // wave q: pixel row q
    const int w0 = bx * TX, h0 = by * TY;
    const float* __restrict__ xn = x + (size_t)n * Cc * HW;

    // A-frags (18 x dwordx4, L2-hot)
    bf16x8 af[NKB];
#pragma unroll
    for (int kb = 0; kb < NKB; ++kb)
        af[kb] = *(const bf16x8*)(blob + (kb * 64 + lane) * 8);

    // ---- stage tile: (col, row, cgrp) -> 8 ch per b128 write, XOR-swizzled ----
#pragma unroll
    for (int i = 0; i < 6; ++i) {
        int idx = tid + i * 512;
        if (idx < NSTG) {
            int col  = idx % SC;
            int rest = idx / SC;
            int row  = rest % SR, cg = rest / SR;
            int gh = h0 + row - 1, gw = w0 + col - 1;
            bool ok = ((unsigned)gh < (unsigned)Hh) && ((unsigned)gw < (unsigned)Ww);
            const float* src = xn + (size_t)(cg * 8) * HW + gh * Ww + gw;
            float v[8];
#pragma unroll
            for (int j = 0; j < 8; ++j)
                v[j] = ok ? src[(size_t)j * HW] : 0.f;
            unsigned u0 = (unsigned)f2b(v[0]) | ((unsigned)f2b(v[1]) << 16);
            unsigned u1 = (unsigned)f2b(v[2]) | ((unsigned)f2b(v[3]) << 16);
            unsigned u2 = (unsigned)f2b(v[4]) | ((unsigned)f2b(v[5]) << 16);
            unsigned u3 = (unsigned)f2b(v[6]) | ((unsigned)f2b(v[7]) << 16);
            int widx = (row * SC + col) * 64 + ((cg ^ (col & 7)) << 3);
            *(int4*)&xs[widx] = make_int4(u0, u1, u2, u3);
        }
    }
    __syncthreads();

    // ---- MFMA: wave q owns pixel row q; px-in-row = (lane&15) + 16*mt ----
    const int g8 = (lane >> 4) << 3;
    int cbase[3], chg[3][2];
#pragma unroll
    for (int dj = 0; dj < 3; ++dj) {
        int swz = (((lane & 15) + dj) & 7) << 3;
        chg[dj][0] = g8 ^ swz;
        chg[dj][1] = (32 | g8) ^ swz;
        cbase[dj]  = (q * SC + (lane & 15) + dj) * 64;
    }

    f32x4 z = {0.f, 0.f, 0.f, 0.f};
    f32x4 acc0 = z, acc1 = z;

#pragma unroll
    for (int kb = 0; kb < NKB; ++kb) {
        const int p = kb >> 1, di = p / 3, dj = p % 3, ch = kb & 1;
        const int a0 = cbase[dj] + di * (SC * 64) + chg[dj][ch];
        bf16x8 b0 = *(const bf16x8*)&xs[a0];              // mt0: cols 0..15
        bf16x8 b1 = *(const bf16x8*)&xs[a0 + 16 * 64];    // mt1: cols 16..31
        acc0 = __builtin_amdgcn_mfma_f32_16x16x32_bf16(af[kb], b0, acc0, 0, 0, 0);
        acc1 = __builtin_amdgcn_mfma_f32_16x16x32_bf16(af[kb], b1, acc1, 0, 0, 0);
    }

    // ---- softmax (shfl over 16/32), filter -> fb[px][k] bf16 ----
    const float g0 = gamma[0];
    const int gidx = lane >> 4;
    const int k0 = gidx * 4;
    const float NEG = -3.0e38f;

    f32x4 accs[2] = {acc0, acc1};
#pragma unroll
    for (int mt = 0; mt < 2; ++mt) {
        float a0 = accs[mt][0], a1 = accs[mt][1], a2 = accs[mt][2], a3 = accs[mt][3];
        float m0 = (gidx < 3) ? a0 : NEG;
        float m1 = (gidx < 2) ? a1 : NEG;
        float m2 = (gidx < 2) ? a2 : NEG;
        float m3 = (gidx < 2) ? a3 : NEG;
        float m = fmaxf(fmaxf(m0, m1), fmaxf(m2, m3));
        m = fmaxf(m, __shfl_xor(m, 16));
        m = fmaxf(m, __shfl_xor(m, 32));
        float e0 = (gidx < 3) ? __expf(a0 - m) : 0.f;
        float e1 = (gidx < 2) ? __expf(a1 - m) : 0.f;
        float e2 = (gidx < 2) ? __expf(a2 - m) : 0.f;
        float e3 = (gidx < 2) ? __expf(a3 - m) : 0.f;
        float s = (e0 + e1) + (e2 + e3);
        s += __shfl_xor(s, 16);
        s += __shfl_xor(s, 32);
        const float gs = g0 / s;
        const int px = q * 32 + mt * 16 + (lane & 15);
        if (gidx < 2) {
            unsigned p01 = (unsigned)f2b(e0 * gs) | ((unsigned)f2b(e1 * gs) << 16);
            unsigned p23 = (unsigned)f2b(e2 * gs) | ((unsigned)f2b(e3 * gs) << 16);
            *(unsigned*)&fb[px * FBS + k0]     = p01;
            *(unsigned*)&fb[px * FBS + k0 + 2] = p23;
        } else if (gidx == 2) {
            fb[px * FBS + 8] = f2b(e0 * gs);
        }
    }
    __syncthreads();

    // ---- combine + residual: thread owns 4 cgroups of one pixel ----
    const int px = tid & 255;                  // waves 0-3: cg 0-3, waves 4-7: cg 4-7
    const int prow = px >> 5, pcol = px & 31;
    const int cg0 = (tid >> 8) << 2;
    float f[9];
    {
        int4 u = *(const int4*)&fb[px * FBS];  // 32-B aligned
        f[0] = b2f((unsigned short)(u.x & 0xffff)); f[1] = b2f((unsigned short)(u.x >> 16));
        f[2] = b2f((unsigned short)(u.y & 0xffff)); f[3] = b2f((unsigned short)(u.y >> 16));
        f[4] = b2f((unsigned short)(u.z & 0xffff)); f[5] = b2f((unsigned short)(u.z >> 16));
        f[6] = b2f((unsigned short)(u.w & 0xffff)); f[7] = b2f((unsigned short)(u.w >> 16));
        f[8] = b2f((unsigned short)fb[px * FBS + 8]);
    }

    float* outp = out + (size_t)n * Cc * HW + (size_t)(h0 + prow) * Ww + (w0 + pcol);

#pragma unroll
    for (int cgi = 0; cgi < 4; ++cgi) {
        const int cg = cg0 + cgi;
        float acc[8], cen[8];
#pragma unroll
        for (int j = 0; j < 8; ++j) acc[j] = 0.f;
#pragma unroll
        for (int p = 0; p < 9; ++p) {
            const int di = p / 3, dj = p % 3;
            const int addr = ((prow + di) * SC + pcol + dj) * 64
                           + ((cg ^ ((pcol + dj) & 7)) << 3);
            int4 u = *(const int4*)&xs[addr];
            float v[8];
            v[0] = b2f((unsigned short)(u.x & 0xffff)); v[1] = b2f((unsigned short)(u.x >> 16));
            v[2] = b2f((unsigned short)(u.y & 0xffff)); v[3] = b2f((unsigned short)(u.y >> 16));
            v[4] = b2f((unsigned short)(u.z & 0xffff)); v[5] = b2f((unsigned short)(u.z >> 16));
            v[6] = b2f((unsigned short)(u.w & 0xffff)); v[7] = b2f((unsigned short)(u.w >> 16));
#pragma unroll
            for (int j = 0; j < 8; ++j) {
                if (p == 4) cen[j] = v[j];
                acc[j] = fmaf(f[p], v[j], acc[j]);
            }
        }
#pragma unroll
        for (int j = 0; j < 8; ++j)
            outp[(size_t)(cg * 8 + j) * HW] = acc[j] + cen[j];
    }
}

extern "C" void kernel_launch(void* const* d_in, const int* in_sizes, int n_in,
                              void* d_out, int out_size, void* d_ws, size_t ws_size,
                              hipStream_t stream) {
    const float* x  = (const float*)d_in[0];
    const float* cw = (const float*)d_in[1];
    const float* gm = (const float*)d_in[2];
    float* out = (float*)d_out;
    unsigned short* blob = (unsigned short*)d_ws;   // 9216 bf16 = 18 KB

    k_wprep<<<dim3((BLOB_N + 255) / 256), dim3(256), 0, stream>>>(cw, blob);
    k_main <<<dim3(NWG), dim3(512), 0, stream>>>(x, blob, gm, out);
}

// Round 10
// 45.782 us; speedup vs baseline: 2.4437x; 1.2357x over previous
//
#include <hip/hip_runtime.h>

// DynamicWeights, fully fused MFMA kernel + weight-prep. R10 = R9 with the
// register budget fixed: __launch_bounds__(512,4) so the 18 A-fragments stay
// in VGPRs (R9's (512,6) forced a 46MB scratch spill of af[]).
//  K0 k_wprep: weights -> MFMA A-fragment blob (bf16), rows 9..15 zeroed.
//  K1 k_main: stage x-tile (32x8 px + halo, 64ch, bf16, XOR-swizzled) in LDS;
//     conv via mfma_f32_16x16x32_bf16 (wave q: pixel row q, 2 m-tiles);
//     softmax via shfl; filter -> fb (bf16); combine + residual from the SAME
//     LDS tile; coalesced dword stores. XCD-aware block swizzle.
// x: (8,64,192,192) f32, conv_w: (9,64,3,3) f32, gamma: (1,) f32

constexpr int Nn = 8, Cc = 64, Hh = 192, Ww = 192;
constexpr int HW  = Hh * Ww;
constexpr int NKB = 18;                 // K-blocks: 576/32
constexpr int BLOB_N = NKB * 64 * 8;    // 9216 bf16
constexpr int TX = 32, TY = 8;          // pixel tile (256 px)
constexpr int SR = TY + 2, SC = TX + 2; // staged rows/cols: 10 x 34
constexpr int NSTG = SR * SC * 8;       // 2720 b128 stores (8ch each)
constexpr int FBS = 16;                 // fbuf stride (shorts) per pixel
constexpr int GX = Ww / TX, GY = Hh / TY;          // 6, 24
constexpr int NWG = GX * GY * Nn;                  // 1152 (% 8 == 0)
constexpr int CPX = NWG / 8;                       // 144 tiles per XCD chunk

typedef short  bf16x8 __attribute__((ext_vector_type(8)));
typedef float  f32x4  __attribute__((ext_vector_type(4)));

__device__ __forceinline__ unsigned short f2b(float f) {
    union { float f; unsigned u; } v; v.f = f;
    return (unsigned short)((v.u + 0x7FFF + ((v.u >> 16) & 1)) >> 16);
}
__device__ __forceinline__ float b2f(unsigned short s) {
    union { unsigned u; float f; } v; v.u = ((unsigned)s) << 16;
    return v.f;
}

// ---- K0: weight blob in A-fragment layout (validated R7/R8) ----
__global__ __launch_bounds__(256)
void k_wprep(const float* __restrict__ cw, unsigned short* __restrict__ blob) {
    int idx = blockIdx.x * 256 + threadIdx.x;
    if (idx < BLOB_N) {
        int j  = idx & 7;
        int l  = (idx >> 3) & 63;
        int kb = idx >> 9;
        int k  = kb * 32 + ((l >> 4) << 3) + j;
        int m  = l & 15;
        int p  = k >> 6, c = k & 63;
        float v = (m < 9) ? cw[(m * Cc + c) * 9 + p] : 0.f;
        blob[idx] = f2b(v);
    }
}

// ---- K1: fused conv + softmax + combine, 8 waves/block ----
__global__ __launch_bounds__(512, 4)   // 128 VGPR cap: af[18] stays in registers
void k_main(const float* __restrict__ x, const unsigned short* __restrict__ blob,
            const float* __restrict__ gamma, float* __restrict__ out)
{
    __shared__ short xs[SR * SC * 64];   // 43520 B, swizzled [row][col][ch]
    __shared__ short fb[256 * FBS];      // 8192 B: per-pixel 9 filter taps (bf16)

    // XCD-aware bijective swizzle (1152 % 8 == 0): XCD k gets 144 contiguous tiles
    const int b  = blockIdx.x;
    const int wt = (b & 7) * CPX + (b >> 3);
    const int bx = wt % GX;
    const int r2 = wt / GX;
    const int by = r2 % GY;
    const int n  = r2 / GY;

    const int tid  = threadIdx.x;
    const int lane = tid & 63, q = tid >> 6;       // wave q: pixel row q
    const int w0 = bx * TX, h0 = by * TY;
    const float* __restrict__ xn = x + (size_t)n * Cc * HW;

    // A-frags (18 x dwordx4, L2-hot)
    bf16x8 af[NKB];
#pragma unroll
    for (int kb = 0; kb < NKB; ++kb)
        af[kb] = *(const bf16x8*)(blob + (kb * 64 + lane) * 8);

    // ---- stage tile: (col, row, cgrp) -> 8 ch per b128 write, XOR-swizzled ----
#pragma unroll
    for (int i = 0; i < 6; ++i) {
        int idx = tid + i * 512;
        if (idx < NSTG) {
            int col  = idx % SC;
            int rest = idx / SC;
            int row  = rest % SR, cg = rest / SR;
            int gh = h0 + row - 1, gw = w0 + col - 1;
            bool ok = ((unsigned)gh < (unsigned)Hh) && ((unsigned)gw < (unsigned)Ww);
            const float* src = xn + (size_t)(cg * 8) * HW + gh * Ww + gw;
            float v[8];
#pragma unroll
            for (int j = 0; j < 8; ++j)
                v[j] = ok ? src[(size_t)j * HW] : 0.f;
            unsigned u0 = (unsigned)f2b(v[0]) | ((unsigned)f2b(v[1]) << 16);
            unsigned u1 = (unsigned)f2b(v[2]) | ((unsigned)f2b(v[3]) << 16);
            unsigned u2 = (unsigned)f2b(v[4]) | ((unsigned)f2b(v[5]) << 16);
            unsigned u3 = (unsigned)f2b(v[6]) | ((unsigned)f2b(v[7]) << 16);
            int widx = (row * SC + col) * 64 + ((cg ^ (col & 7)) << 3);
            *(int4*)&xs[widx] = make_int4(u0, u1, u2, u3);
        }
    }
    __syncthreads();

    // ---- MFMA: wave q owns pixel row q; px-in-row = (lane&15) + 16*mt ----
    const int g8 = (lane >> 4) << 3;
    int cbase[3], chg[3][2];
#pragma unroll
    for (int dj = 0; dj < 3; ++dj) {
        int swz = (((lane & 15) + dj) & 7) << 3;
        chg[dj][0] = g8 ^ swz;
        chg[dj][1] = (32 | g8) ^ swz;
        cbase[dj]  = (q * SC + (lane & 15) + dj) * 64;
    }

    f32x4 z = {0.f, 0.f, 0.f, 0.f};
    f32x4 acc0 = z, acc1 = z;

#pragma unroll
    for (int kb = 0; kb < NKB; ++kb) {
        const int p = kb >> 1, di = p / 3, dj = p % 3, ch = kb & 1;
        const int a0 = cbase[dj] + di * (SC * 64) + chg[dj][ch];
        bf16x8 b0 = *(const bf16x8*)&xs[a0];              // mt0: cols 0..15
        bf16x8 b1 = *(const bf16x8*)&xs[a0 + 16 * 64];    // mt1: cols 16..31
        acc0 = __builtin_amdgcn_mfma_f32_16x16x32_bf16(af[kb], b0, acc0, 0, 0, 0);
        acc1 = __builtin_amdgcn_mfma_f32_16x16x32_bf16(af[kb], b1, acc1, 0, 0, 0);
    }

    // ---- softmax (shfl over 16/32), filter -> fb[px][k] bf16 ----
    const float g0 = gamma[0];
    const int gidx = lane >> 4;
    const int k0 = gidx * 4;
    const float NEG = -3.0e38f;

    f32x4 accs[2] = {acc0, acc1};
#pragma unroll
    for (int mt = 0; mt < 2; ++mt) {
        float a0 = accs[mt][0], a1 = accs[mt][1], a2 = accs[mt][2], a3 = accs[mt][3];
        float m0 = (gidx < 3) ? a0 : NEG;
        float m1 = (gidx < 2) ? a1 : NEG;
        float m2 = (gidx < 2) ? a2 : NEG;
        float m3 = (gidx < 2) ? a3 : NEG;
        float m = fmaxf(fmaxf(m0, m1), fmaxf(m2, m3));
        m = fmaxf(m, __shfl_xor(m, 16));
        m = fmaxf(m, __shfl_xor(m, 32));
        float e0 = (gidx < 3) ? __expf(a0 - m) : 0.f;
        float e1 = (gidx < 2) ? __expf(a1 - m) : 0.f;
        float e2 = (gidx < 2) ? __expf(a2 - m) : 0.f;
        float e3 = (gidx < 2) ? __expf(a3 - m) : 0.f;
        float s = (e0 + e1) + (e2 + e3);
        s += __shfl_xor(s, 16);
        s += __shfl_xor(s, 32);
        const float gs = g0 / s;
        const int px = q * 32 + mt * 16 + (lane & 15);
        if (gidx < 2) {
            unsigned p01 = (unsigned)f2b(e0 * gs) | ((unsigned)f2b(e1 * gs) << 16);
            unsigned p23 = (unsigned)f2b(e2 * gs) | ((unsigned)f2b(e3 * gs) << 16);
            *(unsigned*)&fb[px * FBS + k0]     = p01;
            *(unsigned*)&fb[px * FBS + k0 + 2] = p23;
        } else if (gidx == 2) {
            fb[px * FBS + 8] = f2b(e0 * gs);
        }
    }
    __syncthreads();

    // ---- combine + residual: thread owns 4 cgroups of one pixel ----
    const int px = tid & 255;                  // waves 0-3: cg 0-3, waves 4-7: cg 4-7
    const int prow = px >> 5, pcol = px & 31;
    const int cg0 = (tid >> 8) << 2;
    float f[9];
    {
        int4 u = *(const int4*)&fb[px * FBS];  // 32-B aligned
        f[0] = b2f((unsigned short)(u.x & 0xffff)); f[1] = b2f((unsigned short)(u.x >> 16));
        f[2] = b2f((unsigned short)(u.y & 0xffff)); f[3] = b2f((unsigned short)(u.y >> 16));
        f[4] = b2f((unsigned short)(u.z & 0xffff)); f[5] = b2f((unsigned short)(u.z >> 16));
        f[6] = b2f((unsigned short)(u.w & 0xffff)); f[7] = b2f((unsigned short)(u.w >> 16));
        f[8] = b2f((unsigned short)fb[px * FBS + 8]);
    }

    float* outp = out + (size_t)n * Cc * HW + (size_t)(h0 + prow) * Ww + (w0 + pcol);

#pragma unroll
    for (int cgi = 0; cgi < 4; ++cgi) {
        const int cg = cg0 + cgi;
        float acc[8], cen[8];
#pragma unroll
        for (int j = 0; j < 8; ++j) acc[j] = 0.f;
#pragma unroll
        for (int p = 0; p < 9; ++p) {
            const int di = p / 3, dj = p % 3;
            const int addr = ((prow + di) * SC + pcol + dj) * 64
                           + ((cg ^ ((pcol + dj) & 7)) << 3);
            int4 u = *(const int4*)&xs[addr];
            float v[8];
            v[0] = b2f((unsigned short)(u.x & 0xffff)); v[1] = b2f((unsigned short)(u.x >> 16));
            v[2] = b2f((unsigned short)(u.y & 0xffff)); v[3] = b2f((unsigned short)(u.y >> 16));
            v[4] = b2f((unsigned short)(u.z & 0xffff)); v[5] = b2f((unsigned short)(u.z >> 16));
            v[6] = b2f((unsigned short)(u.w & 0xffff)); v[7] = b2f((unsigned short)(u.w >> 16));
#pragma unroll
            for (int j = 0; j < 8; ++j) {
                if (p == 4) cen[j] = v[j];
                acc[j] = fmaf(f[p], v[j], acc[j]);
            }
        }
#pragma unroll
        for (int j = 0; j < 8; ++j)
            outp[(size_t)(cg * 8 + j) * HW] = acc[j] + cen[j];
    }
}

extern "C" void kernel_launch(void* const* d_in, const int* in_sizes, int n_in,
                              void* d_out, int out_size, void* d_ws, size_t ws_size,
                              hipStream_t stream) {
    const float* x  = (const float*)d_in[0];
    const float* cw = (const float*)d_in[1];
    const float* gm = (const float*)d_in[2];
    float* out = (float*)d_out;
    unsigned short* blob = (unsigned short*)d_ws;   // 9216 bf16 = 18 KB

    k_wprep<<<dim3((BLOB_N + 255) / 256), dim3(256), 0, stream>>>(cw, blob);
    k_main <<<dim3(NWG), dim3(512), 0, stream>>>(x, blob, gm, out);
}

// Round 12
// 44.268 us; speedup vs baseline: 2.5273x; 1.0342x over previous
//
#include <hip/hip_runtime.h>

// DynamicWeights, fully fused MFMA kernel + weight-prep. R12 = R11 with the
// cvt_pkrtz type fixed (__fp16 vector return, bit-cast via union).
// LDS tile / weight blob / filter buffer in f16:
//   - staging pack via v_cvt_pkrtz_f16_f32 (1 inst per pair)
//   - combine unpack via v_cvt_f32_f16 / v_fma_mix_f32 (compiler-fused)
//   - mfma_f32_16x16x32_f16 (same shape & fragment layout as bf16 variant)
//  K0 k_wprep: weights -> MFMA A-fragment blob (f16), rows 9..15 zeroed.
//  K1 k_main: stage x-tile (32x8 px + halo, 64ch, f16, XOR-swizzled) in LDS;
//     conv via MFMA (wave q: pixel row q, 2 m-tiles); softmax via shfl;
//     filter -> fb (f16); combine + residual from the SAME LDS tile.
// x: (8,64,192,192) f32, conv_w: (9,64,3,3) f32, gamma: (1,) f32

constexpr int Nn = 8, Cc = 64, Hh = 192, Ww = 192;
constexpr int HW  = Hh * Ww;
constexpr int NKB = 18;                 // K-blocks: 576/32
constexpr int BLOB_N = NKB * 64 * 8;    // 9216 f16
constexpr int TX = 32, TY = 8;          // pixel tile (256 px)
constexpr int SR = TY + 2, SC = TX + 2; // staged rows/cols: 10 x 34
constexpr int NSTG = SR * SC * 8;       // 2720 b128 stores (8ch each)
constexpr int FBS = 16;                 // fbuf stride (shorts) per pixel
constexpr int GX = Ww / TX, GY = Hh / TY;          // 6, 24
constexpr int NWG = GX * GY * Nn;                  // 1152 (% 8 == 0)
constexpr int CPX = NWG / 8;                       // 144 tiles per XCD chunk

typedef _Float16 f16x8 __attribute__((ext_vector_type(8)));
typedef float    f32x4 __attribute__((ext_vector_type(4)));
typedef __fp16   fp16x2 __attribute__((ext_vector_type(2)));

__device__ __forceinline__ unsigned pkh(float a, float b) {
    fp16x2 h = __builtin_amdgcn_cvt_pkrtz(a, b);   // 1 inst: cvt+pack pair
    union { fp16x2 h; unsigned u; } v; v.h = h;
    return v.u;
}
__device__ __forceinline__ unsigned short f2h(float f) {
    union { _Float16 h; unsigned short s; } v; v.h = (_Float16)f;
    return v.s;
}
__device__ __forceinline__ float h2f(unsigned short s) {
    union { unsigned short s; _Float16 h; } v; v.s = s;
    return (float)v.h;
}

// ---- K0: weight blob in A-fragment layout (layout validated R7-R10) ----
__global__ __launch_bounds__(256)
void k_wprep(const float* __restrict__ cw, unsigned short* __restrict__ blob) {
    int idx = blockIdx.x * 256 + threadIdx.x;
    if (idx < BLOB_N) {
        int j  = idx & 7;
        int l  = (idx >> 3) & 63;
        int kb = idx >> 9;
        int k  = kb * 32 + ((l >> 4) << 3) + j;
        int m  = l & 15;
        int p  = k >> 6, c = k & 63;
        float v = (m < 9) ? cw[(m * Cc + c) * 9 + p] : 0.f;
        blob[idx] = f2h(v);
    }
}

// ---- K1: fused conv + softmax + combine, 8 waves/block ----
__global__ __launch_bounds__(512, 4)   // 128 VGPR cap: af[18] stays in registers
void k_main(const float* __restrict__ x, const unsigned short* __restrict__ blob,
            const float* __restrict__ gamma, float* __restrict__ out)
{
    __shared__ short xs[SR * SC * 64];   // 43520 B, swizzled [row][col][ch], f16
    __shared__ short fb[256 * FBS];      // 8192 B: per-pixel 9 filter taps (f16)

    // XCD-aware bijective swizzle (1152 % 8 == 0)
    const int b  = blockIdx.x;
    const int wt = (b & 7) * CPX + (b >> 3);
    const int bx = wt % GX;
    const int r2 = wt / GX;
    const int by = r2 % GY;
    const int n  = r2 / GY;

    const int tid  = threadIdx.x;
    const int lane = tid & 63, q = tid >> 6;       // wave q: pixel row q
    const int w0 = bx * TX, h0 = by * TY;
    const float* __restrict__ xn = x + (size_t)n * Cc * HW;

    // A-frags (18 x dwordx4, L2-hot)
    f16x8 af[NKB];
#pragma unroll
    for (int kb = 0; kb < NKB; ++kb)
        af[kb] = *(const f16x8*)(blob + (kb * 64 + lane) * 8);

    // ---- stage tile: (col, row, cgrp) -> 8 ch per b128 write, XOR-swizzled ----
#pragma unroll
    for (int i = 0; i < 6; ++i) {
        int idx = tid + i * 512;
        if (idx < NSTG) {
            int col  = idx % SC;
            int rest = idx / SC;
            int row  = rest % SR, cg = rest / SR;
            int gh = h0 + row - 1, gw = w0 + col - 1;
            bool ok = ((unsigned)gh < (unsigned)Hh) && ((unsigned)gw < (unsigned)Ww);
            const float* src = xn + (size_t)(cg * 8) * HW + gh * Ww + gw;
            float v[8];
#pragma unroll
            for (int j = 0; j < 8; ++j)
                v[j] = ok ? src[(size_t)j * HW] : 0.f;
            int widx = (row * SC + col) * 64 + ((cg ^ (col & 7)) << 3);
            *(int4*)&xs[widx] = make_int4(pkh(v[0], v[1]), pkh(v[2], v[3]),
                                          pkh(v[4], v[5]), pkh(v[6], v[7]));
        }
    }
    __syncthreads();

    // ---- MFMA: wave q owns pixel row q; px-in-row = (lane&15) + 16*mt ----
    const int g8 = (lane >> 4) << 3;
    int cbase[3], chg[3][2];
#pragma unroll
    for (int dj = 0; dj < 3; ++dj) {
        int swz = (((lane & 15) + dj) & 7) << 3;
        chg[dj][0] = g8 ^ swz;
        chg[dj][1] = (32 | g8) ^ swz;
        cbase[dj]  = (q * SC + (lane & 15) + dj) * 64;
    }

    f32x4 z = {0.f, 0.f, 0.f, 0.f};
    f32x4 acc0 = z, acc1 = z;

#pragma unroll
    for (int kb = 0; kb < NKB; ++kb) {
        const int p = kb >> 1, di = p / 3, dj = p % 3, ch = kb & 1;
        const int a0 = cbase[dj] + di * (SC * 64) + chg[dj][ch];
        f16x8 b0 = *(const f16x8*)&xs[a0];              // mt0: cols 0..15
        f16x8 b1 = *(const f16x8*)&xs[a0 + 16 * 64];    // mt1: cols 16..31
        acc0 = __builtin_amdgcn_mfma_f32_16x16x32_f16(af[kb], b0, acc0, 0, 0, 0);
        acc1 = __builtin_amdgcn_mfma_f32_16x16x32_f16(af[kb], b1, acc1, 0, 0, 0);
    }

    // ---- softmax (shfl over 16/32), filter -> fb[px][k] f16 ----
    const float g0 = gamma[0];
    const int gidx = lane >> 4;
    const int k0 = gidx * 4;
    const float NEG = -3.0e38f;

    f32x4 accs[2] = {acc0, acc1};
#pragma unroll
    for (int mt = 0; mt < 2; ++mt) {
        float a0 = accs[mt][0], a1 = accs[mt][1], a2 = accs[mt][2], a3 = accs[mt][3];
        float m0 = (gidx < 3) ? a0 : NEG;
        float m1 = (gidx < 2) ? a1 : NEG;
        float m2 = (gidx < 2) ? a2 : NEG;
        float m3 = (gidx < 2) ? a3 : NEG;
        float m = fmaxf(fmaxf(m0, m1), fmaxf(m2, m3));
        m = fmaxf(m, __shfl_xor(m, 16));
        m = fmaxf(m, __shfl_xor(m, 32));
        float e0 = (gidx < 3) ? __expf(a0 - m) : 0.f;
        float e1 = (gidx < 2) ? __expf(a1 - m) : 0.f;
        float e2 = (gidx < 2) ? __expf(a2 - m) : 0.f;
        float e3 = (gidx < 2) ? __expf(a3 - m) : 0.f;
        float s = (e0 + e1) + (e2 + e3);
        s += __shfl_xor(s, 16);
        s += __shfl_xor(s, 32);
        const float gs = g0 / s;
        const int px = q * 32 + mt * 16 + (lane & 15);
        if (gidx < 2) {
            *(unsigned*)&fb[px * FBS + k0]     = pkh(e0 * gs, e1 * gs);
            *(unsigned*)&fb[px * FBS + k0 + 2] = pkh(e2 * gs, e3 * gs);
        } else if (gidx == 2) {
            fb[px * FBS + 8] = f2h(e0 * gs);
        }
    }
    __syncthreads();

    // ---- combine + residual: thread owns 4 cgroups of one pixel ----
    const int px = tid & 255;                  // waves 0-3: cg 0-3, waves 4-7: cg 4-7
    const int prow = px >> 5, pcol = px & 31;
    const int cg0 = (tid >> 8) << 2;
    float f[9];
    {
        int4 u = *(const int4*)&fb[px * FBS];  // 32-B aligned
        union { int4 i; f16x8 h; } cv; cv.i = u;
#pragma unroll
        for (int k = 0; k < 8; ++k) f[k] = (float)cv.h[k];
        f[8] = h2f((unsigned short)fb[px * FBS + 8]);
    }

    float* outp = out + (size_t)n * Cc * HW + (size_t)(h0 + prow) * Ww + (w0 + pcol);

#pragma unroll
    for (int cgi = 0; cgi < 4; ++cgi) {
        const int cg = cg0 + cgi;
        float acc[8], cen[8];
#pragma unroll
        for (int j = 0; j < 8; ++j) acc[j] = 0.f;
#pragma unroll
        for (int p = 0; p < 9; ++p) {
            const int di = p / 3, dj = p % 3;
            const int addr = ((prow + di) * SC + pcol + dj) * 64
                           + ((cg ^ ((pcol + dj) & 7)) << 3);
            union { int4 i; f16x8 h; } cv; cv.i = *(const int4*)&xs[addr];
#pragma unroll
            for (int j = 0; j < 8; ++j) {
                float v = (float)cv.h[j];              // fuses into v_fma_mix
                if (p == 4) cen[j] = v;
                acc[j] = fmaf(f[p], v, acc[j]);
            }
        }
#pragma unroll
        for (int j = 0; j < 8; ++j)
            outp[(size_t)(cg * 8 + j) * HW] = acc[j] + cen[j];
    }
}

extern "C" void kernel_launch(void* const* d_in, const int* in_sizes, int n_in,
                              void* d_out, int out_size, void* d_ws, size_t ws_size,
                              hipStream_t stream) {
    const float* x  = (const float*)d_in[0];
    const float* cw = (const float*)d_in[1];
    const float* gm = (const float*)d_in[2];
    float* out = (float*)d_out;
    unsigned short* blob = (unsigned short*)d_ws;   // 9216 f16 = 18 KB

    k_wprep<<<dim3((BLOB_N + 255) / 256), dim3(256), 0, stream>>>(cw, blob);
    k_main <<<dim3(NWG), dim3(512), 0, stream>>>(x, blob, gm, out);
}

// Round 13
// 43.548 us; speedup vs baseline: 2.5691x; 1.0165x over previous
//
#include <hip/hip_runtime.h>

// DynamicWeights, fully fused MFMA kernel + weight-prep. R13 = R12 minus the
// second barrier: wave q combines its OWN pixel row q, so the filter buffer
// round-trip is wave-local (ds write -> lgkmcnt -> ds read, no s_barrier) and
// waves desynchronize after softmax (stage/MFMA/combine phases co-schedule).
// Combine also tap-shares: each lane owns an adjacent pixel PAIR x 2 cgroups
// (12 b128 per cg serve both pixels), stores as float2.
//  K0 k_wprep: weights -> MFMA A-fragment blob (f16), rows 9..15 zeroed.
//  K1 k_main: stage x-tile (32x8 px + halo, 64ch, f16, XOR-swizzled) in LDS;
//     conv via mfma_f32_16x16x32_f16; softmax via shfl; combine + residual
//     from the SAME LDS tile. ONE barrier total.
// x: (8,64,192,192) f32, conv_w: (9,64,3,3) f32, gamma: (1,) f32

constexpr int Nn = 8, Cc = 64, Hh = 192, Ww = 192;
constexpr int HW  = Hh * Ww;
constexpr int NKB = 18;                 // K-blocks: 576/32
constexpr int BLOB_N = NKB * 64 * 8;    // 9216 f16
constexpr int TX = 32, TY = 8;          // pixel tile (256 px)
constexpr int SR = TY + 2, SC = TX + 2; // staged rows/cols: 10 x 34
constexpr int NSTG = SR * SC * 8;       // 2720 b128 stores (8ch each)
constexpr int FBS = 16;                 // fbuf stride (shorts) per pixel
constexpr int GX = Ww / TX, GY = Hh / TY;          // 6, 24
constexpr int NWG = GX * GY * Nn;                  // 1152 (% 8 == 0)
constexpr int CPX = NWG / 8;                       // 144 tiles per XCD chunk

typedef _Float16 f16x8 __attribute__((ext_vector_type(8)));
typedef float    f32x4 __attribute__((ext_vector_type(4)));
typedef __fp16   fp16x2 __attribute__((ext_vector_type(2)));

__device__ __forceinline__ unsigned pkh(float a, float b) {
    fp16x2 h = __builtin_amdgcn_cvt_pkrtz(a, b);   // 1 inst: cvt+pack pair
    union { fp16x2 h; unsigned u; } v; v.h = h;
    return v.u;
}
__device__ __forceinline__ unsigned short f2h(float f) {
    union { _Float16 h; unsigned short s; } v; v.h = (_Float16)f;
    return v.s;
}
__device__ __forceinline__ float h2f(unsigned short s) {
    union { unsigned short s; _Float16 h; } v; v.s = s;
    return (float)v.h;
}

// ---- K0: weight blob in A-fragment layout (layout validated R7-R12) ----
__global__ __launch_bounds__(256)
void k_wprep(const float* __restrict__ cw, unsigned short* __restrict__ blob) {
    int idx = blockIdx.x * 256 + threadIdx.x;
    if (idx < BLOB_N) {
        int j  = idx & 7;
        int l  = (idx >> 3) & 63;
        int kb = idx >> 9;
        int k  = kb * 32 + ((l >> 4) << 3) + j;
        int m  = l & 15;
        int p  = k >> 6, c = k & 63;
        float v = (m < 9) ? cw[(m * Cc + c) * 9 + p] : 0.f;
        blob[idx] = f2h(v);
    }
}

// ---- K1: fused conv + softmax + combine, 8 waves/block, ONE barrier ----
__global__ __launch_bounds__(512, 4)   // 128 VGPR cap: af[18] stays in registers
void k_main(const float* __restrict__ x, const unsigned short* __restrict__ blob,
            const float* __restrict__ gamma, float* __restrict__ out)
{
    __shared__ short xs[SR * SC * 64];   // 43520 B, swizzled [row][col][ch], f16
    __shared__ short fb[256 * FBS];      // 8192 B: per-pixel 9 filter taps (f16)

    // XCD-aware bijective swizzle (1152 % 8 == 0)
    const int b  = blockIdx.x;
    const int wt = (b & 7) * CPX + (b >> 3);
    const int bx = wt % GX;
    const int r2 = wt / GX;
    const int by = r2 % GY;
    const int n  = r2 / GY;

    const int tid  = threadIdx.x;
    const int lane = tid & 63, q = tid >> 6;       // wave q: pixel row q
    const int w0 = bx * TX, h0 = by * TY;
    const float* __restrict__ xn = x + (size_t)n * Cc * HW;

    // A-frags (18 x dwordx4, L2-hot)
    f16x8 af[NKB];
#pragma unroll
    for (int kb = 0; kb < NKB; ++kb)
        af[kb] = *(const f16x8*)(blob + (kb * 64 + lane) * 8);

    // ---- stage tile: (col, row, cgrp) -> 8 ch per b128 write, XOR-swizzled ----
#pragma unroll
    for (int i = 0; i < 6; ++i) {
        int idx = tid + i * 512;
        if (idx < NSTG) {
            int col  = idx % SC;
            int rest = idx / SC;
            int row  = rest % SR, cg = rest / SR;
            int gh = h0 + row - 1, gw = w0 + col - 1;
            bool ok = ((unsigned)gh < (unsigned)Hh) && ((unsigned)gw < (unsigned)Ww);
            const float* src = xn + (size_t)(cg * 8) * HW + gh * Ww + gw;
            float v[8];
#pragma unroll
            for (int j = 0; j < 8; ++j)
                v[j] = ok ? src[(size_t)j * HW] : 0.f;
            int widx = (row * SC + col) * 64 + ((cg ^ (col & 7)) << 3);
            *(int4*)&xs[widx] = make_int4(pkh(v[0], v[1]), pkh(v[2], v[3]),
                                          pkh(v[4], v[5]), pkh(v[6], v[7]));
        }
    }
    __syncthreads();   // the ONLY barrier

    // ---- MFMA: wave q owns pixel row q; px-in-row = (lane&15) + 16*mt ----
    const int g8 = (lane >> 4) << 3;
    int cbase[3], chg[3][2];
#pragma unroll
    for (int dj = 0; dj < 3; ++dj) {
        int swz = (((lane & 15) + dj) & 7) << 3;
        chg[dj][0] = g8 ^ swz;
        chg[dj][1] = (32 | g8) ^ swz;
        cbase[dj]  = (q * SC + (lane & 15) + dj) * 64;
    }

    f32x4 z = {0.f, 0.f, 0.f, 0.f};
    f32x4 acc0 = z, acc1 = z;

#pragma unroll
    for (int kb = 0; kb < NKB; ++kb) {
        const int p = kb >> 1, di = p / 3, dj = p % 3, ch = kb & 1;
        const int a0 = cbase[dj] + di * (SC * 64) + chg[dj][ch];
        f16x8 b0 = *(const f16x8*)&xs[a0];              // mt0: cols 0..15
        f16x8 b1 = *(const f16x8*)&xs[a0 + 16 * 64];    // mt1: cols 16..31
        acc0 = __builtin_amdgcn_mfma_f32_16x16x32_f16(af[kb], b0, acc0, 0, 0, 0);
        acc1 = __builtin_amdgcn_mfma_f32_16x16x32_f16(af[kb], b1, acc1, 0, 0, 0);
    }

    // ---- softmax (shfl over 16/32), filter -> fb[px][k] f16 (wave-local px) ----
    const float g0 = gamma[0];
    const int gidx = lane >> 4;
    const int k0 = gidx * 4;
    const float NEG = -3.0e38f;

    f32x4 accs[2] = {acc0, acc1};
#pragma unroll
    for (int mt = 0; mt < 2; ++mt) {
        float a0 = accs[mt][0], a1 = accs[mt][1], a2 = accs[mt][2], a3 = accs[mt][3];
        float m0 = (gidx < 3) ? a0 : NEG;
        float m1 = (gidx < 2) ? a1 : NEG;
        float m2 = (gidx < 2) ? a2 : NEG;
        float m3 = (gidx < 2) ? a3 : NEG;
        float m = fmaxf(fmaxf(m0, m1), fmaxf(m2, m3));
        m = fmaxf(m, __shfl_xor(m, 16));
        m = fmaxf(m, __shfl_xor(m, 32));
        float e0 = (gidx < 3) ? __expf(a0 - m) : 0.f;
        float e1 = (gidx < 2) ? __expf(a1 - m) : 0.f;
        float e2 = (gidx < 2) ? __expf(a2 - m) : 0.f;
        float e3 = (gidx < 2) ? __expf(a3 - m) : 0.f;
        float s = (e0 + e1) + (e2 + e3);
        s += __shfl_xor(s, 16);
        s += __shfl_xor(s, 32);
        const float gs = g0 / s;
        const int px = q * 32 + mt * 16 + (lane & 15);
        if (gidx < 2) {
            *(unsigned*)&fb[px * FBS + k0]     = pkh(e0 * gs, e1 * gs);
            *(unsigned*)&fb[px * FBS + k0 + 2] = pkh(e2 * gs, e3 * gs);
        } else if (gidx == 2) {
            fb[px * FBS + 8] = f2h(e0 * gs);
        }
    }
    // NO barrier: wave q reads back only row-q filters (lgkmcnt orders DS ops)

    // ---- combine + residual: lane owns adjacent px pair x 2 cgroups ----
    const int p0  = 2 * (lane & 15);           // pixel cols p0, p0+1 (0..30)
    const int cgA = lane >> 4;                  // cgroups cgA, cgA+4

    float fA[9], fB[9];
    {
        const int pxA = q * 32 + p0;
        union { int4 i; f16x8 h; } ca; ca.i = *(const int4*)&fb[pxA * FBS];
        union { int4 i; f16x8 h; } cb; cb.i = *(const int4*)&fb[(pxA + 1) * FBS];
#pragma unroll
        for (int k = 0; k < 8; ++k) { fA[k] = (float)ca.h[k]; fB[k] = (float)cb.h[k]; }
        fA[8] = h2f((unsigned short)fb[pxA * FBS + 8]);
        fB[8] = h2f((unsigned short)fb[(pxA + 1) * FBS + 8]);
    }

    float* outp = out + (size_t)n * Cc * HW + (size_t)(h0 + q) * Ww + (w0 + p0);

#pragma unroll
    for (int cgi = 0; cgi < 2; ++cgi) {
        const int cg = cgA + cgi * 4;
        float acc0c[8], acc1c[8], cen0[8], cen1[8];
#pragma unroll
        for (int j = 0; j < 8; ++j) { acc0c[j] = 0.f; acc1c[j] = 0.f; }
#pragma unroll
        for (int di = 0; di < 3; ++di) {
#pragma unroll
            for (int cc = 0; cc < 4; ++cc) {         // staged cols p0..p0+3
                const int col = p0 + cc;
                const int addr = ((q + di) * SC + col) * 64
                               + ((cg ^ (col & 7)) << 3);
                union { int4 i; f16x8 h; } cv; cv.i = *(const int4*)&xs[addr];
#pragma unroll
                for (int j = 0; j < 8; ++j) {
                    float v = (float)cv.h[j];          // fuses into v_fma_mix
                    if (cc < 3)  acc0c[j] = fmaf(fA[di * 3 + cc],     v, acc0c[j]);
                    if (cc >= 1) acc1c[j] = fmaf(fB[di * 3 + cc - 1], v, acc1c[j]);
                    if (di == 1 && cc == 1) cen0[j] = v;
                    if (di == 1 && cc == 2) cen1[j] = v;
                }
            }
        }
#pragma unroll
        for (int j = 0; j < 8; ++j) {
            float2 o = make_float2(acc0c[j] + cen0[j], acc1c[j] + cen1[j]);
            *(float2*)&outp[(size_t)(cg * 8 + j) * HW] = o;
        }
    }
}

extern "C" void kernel_launch(void* const* d_in, const int* in_sizes, int n_in,
                              void* d_out, int out_size, void* d_ws, size_t ws_size,
                              hipStream_t stream) {
    const float* x  = (const float*)d_in[0];
    const float* cw = (const float*)d_in[1];
    const float* gm = (const float*)d_in[2];
    float* out = (float*)d_out;
    unsigned short* blob = (unsigned short*)d_ws;   // 9216 f16 = 18 KB

    k_wprep<<<dim3((BLOB_N + 255) / 256), dim3(256), 0, stream>>>(cw, blob);
    k_main <<<dim3(NWG), dim3(512), 0, stream>>>(x, blob, gm, out);
}